// Round 1
// baseline (296.819 us; speedup 1.0000x reference)
//
#include <hip/hip_runtime.h>
#include <hip/hip_bf16.h>

// Fused: conv3x3(pad=1) -> maxpool2x2 -> conv3x3(pad=1) -> maxpool2x2
// x: [2,1,4096,4096] f32, W1/W2: [1,1,3,3] f32, out: [2,1,1024,1024] f32.
//
// One block computes a TOH x TOW tile of the final output:
//   stage 1: global x window (4*TOH+6) x (4*TOW+6) -> LDS (zero-filled OOB)
//   stage 2: conv1+pool1 -> h2 tile (2*TOH+2) x (2*TOW+2) in LDS
//            (h2 halo forced to 0 where h2 coords are out of [0,2048) --
//             conv2's zero padding is over h2, NOT over conv1-of-zero-x)
//   stage 3: conv2+pool2 -> registers -> float2 coalesced store

#define TOH 16
#define TOW 32
#define XS_H 70    // 4*TOH + 6
#define XS_W 140   // 4*TOW + 6 = 134, padded to 140 so 4-col groups never read OOB
#define H2_H 34    // 2*TOH + 2
#define H2_W 68    // 2*TOW + 2 = 66, padded to 68 (cols 66,67 written, never read)
#define HIMG 4096
#define WIMG 4096
#define H2DIM 2048
#define ODIM 1024

__global__ __launch_bounds__(256) void fused_conv_pool2(
    const float* __restrict__ x, const float* __restrict__ W1,
    const float* __restrict__ W2, float* __restrict__ out)
{
    __shared__ float xs[XS_H][XS_W];
    __shared__ float h2s[H2_H][H2_W];

    const int tid = threadIdx.x;
    const int ow0 = blockIdx.x * TOW;
    const int oh0 = blockIdx.y * TOH;
    const int n   = blockIdx.z;

    float w1[9], w2[9];
#pragma unroll
    for (int i = 0; i < 9; ++i) { w1[i] = W1[i]; w2[i] = W2[i]; }

    const long imgoff = (long)n * HIMG * WIMG;
    const int gy0 = 4 * oh0 - 3;
    const int gx0 = 4 * ow0 - 3;

    // ---- stage 1: x window -> LDS (guarded, zero pad) ----
    for (int idx = tid; idx < XS_H * XS_W; idx += 256) {
        int ly = idx / XS_W;
        int lx = idx - ly * XS_W;
        int gy = gy0 + ly;
        int gx = gx0 + lx;
        float v = 0.f;
        if ((unsigned)gy < (unsigned)HIMG && (unsigned)gx < (unsigned)WIMG)
            v = x[imgoff + (long)gy * WIMG + gx];
        xs[ly][lx] = v;
    }
    __syncthreads();

    // ---- stage 2: conv1 + pool1 -> h2s ----
    // h2 local (p,q) <-> global (2*oh0-1+p, 2*ow0-1+q), needs xs rows 2p..2p+3, cols 2q..2q+3.
    // Groups of 4 consecutive q share a 4x10 x-window (loaded as float2).
    for (int g = tid; g < H2_H * 17; g += 256) {
        int p  = g / 17;
        int q0 = (g - p * 17) * 4;
        float xw[4][10];
#pragma unroll
        for (int r = 0; r < 4; ++r) {
            const float2* src = (const float2*)&xs[2 * p + r][2 * q0];
#pragma unroll
            for (int c = 0; c < 5; ++c) {
                float2 v = src[c];
                xw[r][2 * c]     = v.x;
                xw[r][2 * c + 1] = v.y;
            }
        }
        const int P = 2 * oh0 - 1 + p;
#pragma unroll
        for (int j = 0; j < 4; ++j) {
            int q = q0 + j;
            int Q = 2 * ow0 - 1 + q;
            float s[2][2];
#pragma unroll
            for (int i = 0; i < 2; ++i)
#pragma unroll
                for (int jj = 0; jj < 2; ++jj) {
                    float acc = 0.f;
#pragma unroll
                    for (int u = 0; u < 3; ++u)
#pragma unroll
                        for (int v = 0; v < 3; ++v)
                            acc = fmaf(xw[i + u][2 * j + jj + v], w1[3 * u + v], acc);
                    s[i][jj] = acc;
                }
            float m = fmaxf(fmaxf(s[0][0], s[0][1]), fmaxf(s[1][0], s[1][1]));
            if ((unsigned)P >= (unsigned)H2DIM || (unsigned)Q >= (unsigned)H2DIM)
                m = 0.f;  // zero padding for conv2 lives in h2 space
            h2s[p][q] = m;
        }
    }
    __syncthreads();

    // ---- stage 3: conv2 + pool2 -> out ----
    // One thread: 2 adjacent output cols. a = tid/16, b0 = (tid%16)*2.
    const int a  = tid >> 4;
    const int b0 = (tid & 15) * 2;
    float hw[4][6];
#pragma unroll
    for (int r = 0; r < 4; ++r) {
        const float2* src = (const float2*)&h2s[2 * a + r][2 * b0];
#pragma unroll
        for (int c = 0; c < 3; ++c) {
            float2 v = src[c];
            hw[r][2 * c]     = v.x;
            hw[r][2 * c + 1] = v.y;
        }
    }
    float2 res;
#pragma unroll
    for (int b = 0; b < 2; ++b) {
        float s[2][2];
#pragma unroll
        for (int i = 0; i < 2; ++i)
#pragma unroll
            for (int j = 0; j < 2; ++j) {
                float acc = 0.f;
#pragma unroll
                for (int u = 0; u < 3; ++u)
#pragma unroll
                    for (int v = 0; v < 3; ++v)
                        acc = fmaf(hw[i + u][2 * b + j + v], w2[3 * u + v], acc);
                s[i][j] = acc;
            }
        float m = fmaxf(fmaxf(s[0][0], s[0][1]), fmaxf(s[1][0], s[1][1]));
        ((float*)&res)[b] = m;
    }
    const long obase = (long)n * ODIM * ODIM + (long)(oh0 + a) * ODIM + (ow0 + b0);
    *(float2*)&out[obase] = res;
}

extern "C" void kernel_launch(void* const* d_in, const int* in_sizes, int n_in,
                              void* d_out, int out_size, void* d_ws, size_t ws_size,
                              hipStream_t stream) {
    const float* x  = (const float*)d_in[0];
    const float* W1 = (const float*)d_in[1];
    const float* W2 = (const float*)d_in[2];
    float* out = (float*)d_out;

    dim3 grid(ODIM / TOW, ODIM / TOH, 2);  // 32 x 64 x 2 = 4096 blocks
    dim3 block(256);
    fused_conv_pool2<<<grid, block, 0, stream>>>(x, W1, W2, out);
}

// Round 2
// 292.596 us; speedup vs baseline: 1.0144x; 1.0144x over previous
//
#include <hip/hip_runtime.h>
#include <hip/hip_bf16.h>

// Fused conv3x3(pad1) -> maxpool2x2 -> conv3x3(pad1) -> maxpool2x2
// x: [2,1,4096,4096] f32, W1/W2: [1,1,3,3] f32, out: [2,1,1024,1024] f32.
//
// Round-2 changes vs round-1 (148 us, 31% occ, latency-bound):
//  - h2 tile aliased into the x-stage LDS buffer: 48.6 KB -> 38.1 KB LDS
//    => 4 blocks/CU (16 waves/CU) instead of 3.
//  - interior blocks stage x via __builtin_amdgcn_global_load_lds (16B DMA,
//    no guards, no VGPR round-trip): ~10 issues/thread vs 37 guarded scalars.
//  - 16B-aligned global base (window shifted left 1 col; taps re-derived).

#define HIMG   4096
#define H2DIM  2048
#define ODIM   1024
#define TOH    16
#define TOW    32
#define XS_H   70                 // 4*TOH + 6
#define XS_W4  34                 // float4 per row
#define XS_WF  136                // floats per row (covers gxA .. gxA+135)
#define XS_SLOTS (XS_H * XS_W4)   // 2380 float4 DMA slots
#define SMEM_FLOATS 9536          // 70*136 = 9520 (+16 pad: m=16 group over-reads)
#define H2_W   68
#define NGRP   578                // 34 rows * 17 col-groups

typedef float f4 __attribute__((ext_vector_type(4)));
typedef __attribute__((address_space(3))) void lds_t;
typedef const __attribute__((address_space(1))) void glb_t;

__global__ __launch_bounds__(256, 4) void fused_conv_pool2(
    const float* __restrict__ x, const float* __restrict__ W1,
    const float* __restrict__ W2, float* __restrict__ out)
{
    __shared__ float smem[SMEM_FLOATS];
    const int tid = threadIdx.x;
    const int bx = blockIdx.x, by = blockIdx.y;
    const int n  = blockIdx.z;
    const int ow0 = bx * TOW, oh0 = by * TOH;
    const bool edge = (bx == 0) | (bx == 31) | (by == 0) | (by == 63);

    float w1[9], w2[9];
#pragma unroll
    for (int i = 0; i < 9; ++i) { w1[i] = W1[i]; w2[i] = W2[i]; }

    const long imgoff = (long)n * HIMG * HIMG;
    const int gy0 = 4 * oh0 - 3;      // first x row staged
    const int gxA = 4 * ow0 - 4;      // first x col staged (16B aligned)

    // ---- stage 1: x window -> LDS ----
    if (!edge) {
        const float* gbase = x + imgoff + (long)gy0 * HIMG + gxA;
        for (int idx = tid; idx < XS_SLOTS; idx += 256) {
            int row = idx / XS_W4;
            int c4  = idx - row * XS_W4;
            const float* gp = gbase + row * HIMG + c4 * 4;
            __builtin_amdgcn_global_load_lds((glb_t*)gp, (lds_t*)&smem[idx * 4],
                                             16, 0, 0);
        }
    } else {
        for (int idx = tid; idx < XS_H * XS_WF; idx += 256) {
            int row = idx / XS_WF;
            int col = idx - row * XS_WF;
            int gy = gy0 + row, gx = gxA + col;
            float v = 0.f;
            if ((unsigned)gy < (unsigned)HIMG && (unsigned)gx < (unsigned)HIMG)
                v = x[imgoff + (long)gy * HIMG + gx];
            smem[idx] = v;
        }
    }
    __syncthreads();

    // ---- stage 2: conv1 + pool1 -> registers ----
    // group g: h2 local row p = g/17, col-group m = g%17 covers h2 cols 4m..4m+3.
    // x window: local cols 8m .. 8m+11 (12 floats), rows 2p..2p+3.
    // tap for (pool-row i, pool-col jj, conv v): xw[i+u][2j+1+jj+v]
    float h2r[3][4];
#pragma unroll
    for (int k = 0; k < 3; ++k) {
        int g = tid + k * 256;
        const bool act = g < NGRP;
        int gg = act ? g : 0;
        int p = gg / 17;
        int m = gg - p * 17;
        float xw[4][12];
#pragma unroll
        for (int r = 0; r < 4; ++r) {
            const float2* src = (const float2*)&smem[(2 * p + r) * XS_WF + 8 * m];
#pragma unroll
            for (int c = 0; c < 6; ++c) {
                float2 v = src[c];
                xw[r][2 * c]     = v.x;
                xw[r][2 * c + 1] = v.y;
            }
        }
#pragma unroll
        for (int j = 0; j < 4; ++j) {
            float s00 = 0.f, s01 = 0.f, s10 = 0.f, s11 = 0.f;
#pragma unroll
            for (int u = 0; u < 3; ++u)
#pragma unroll
                for (int v = 0; v < 3; ++v) {
                    float w = w1[3 * u + v];
                    s00 = fmaf(xw[0 + u][2 * j + 1 + v], w, s00);
                    s01 = fmaf(xw[0 + u][2 * j + 2 + v], w, s01);
                    s10 = fmaf(xw[1 + u][2 * j + 1 + v], w, s10);
                    s11 = fmaf(xw[1 + u][2 * j + 2 + v], w, s11);
                }
            float mval = fmaxf(fmaxf(s00, s01), fmaxf(s10, s11));
            if (edge) {
                int P = 2 * oh0 - 1 + p;
                int Q = 2 * ow0 - 1 + 4 * m + j;
                if ((unsigned)P >= (unsigned)H2DIM || (unsigned)Q >= (unsigned)H2DIM)
                    mval = 0.f;   // conv2's zero padding lives in h2 space
            }
            h2r[k][j] = mval;
        }
    }
    __syncthreads();   // all xs reads done; safe to overwrite with h2

    // ---- write h2 -> LDS (aliased over xs) ----
#pragma unroll
    for (int k = 0; k < 3; ++k) {
        int g = tid + k * 256;
        if (g < NGRP) {
            int p = g / 17;
            int m = g - p * 17;
            f4 v;
            v.x = h2r[k][0]; v.y = h2r[k][1]; v.z = h2r[k][2]; v.w = h2r[k][3];
            *(f4*)&smem[p * H2_W + 4 * m] = v;
        }
    }
    __syncthreads();

    // ---- stage 3: conv2 + pool2 -> out ----
    const int a  = tid >> 4;          // output row within tile
    const int b0 = (tid & 15) * 2;    // first of 2 output cols
    float hw[4][6];
#pragma unroll
    for (int r = 0; r < 4; ++r) {
        const float2* src = (const float2*)&smem[(2 * a + r) * H2_W + 2 * b0];
#pragma unroll
        for (int c = 0; c < 3; ++c) {
            float2 v = src[c];
            hw[r][2 * c]     = v.x;
            hw[r][2 * c + 1] = v.y;
        }
    }
    float2 res;
#pragma unroll
    for (int b = 0; b < 2; ++b) {
        float s00 = 0.f, s01 = 0.f, s10 = 0.f, s11 = 0.f;
#pragma unroll
        for (int u = 0; u < 3; ++u)
#pragma unroll
            for (int v = 0; v < 3; ++v) {
                float w = w2[3 * u + v];
                s00 = fmaf(hw[0 + u][2 * b + 0 + v], w, s00);
                s01 = fmaf(hw[0 + u][2 * b + 1 + v], w, s01);
                s10 = fmaf(hw[1 + u][2 * b + 0 + v], w, s10);
                s11 = fmaf(hw[1 + u][2 * b + 1 + v], w, s11);
            }
        float mval = fmaxf(fmaxf(s00, s01), fmaxf(s10, s11));
        ((float*)&res)[b] = mval;
    }
    const long obase = (long)n * ODIM * ODIM + (long)(oh0 + a) * ODIM + (ow0 + b0);
    *(float2*)&out[obase] = res;
}

extern "C" void kernel_launch(void* const* d_in, const int* in_sizes, int n_in,
                              void* d_out, int out_size, void* d_ws, size_t ws_size,
                              hipStream_t stream) {
    const float* x  = (const float*)d_in[0];
    const float* W1 = (const float*)d_in[1];
    const float* W2 = (const float*)d_in[2];
    float* out = (float*)d_out;

    dim3 grid(ODIM / TOW, ODIM / TOH, 2);   // 32 x 64 x 2 = 4096 blocks
    dim3 block(256);
    fused_conv_pool2<<<grid, block, 0, stream>>>(x, W1, W2, out);
}

// Round 3
// 212.246 us; speedup vs baseline: 1.3985x; 1.3786x over previous
//
#include <hip/hip_runtime.h>

// Fused conv3x3(pad1)->maxpool2x2->conv3x3(pad1)->maxpool2x2, fp32.
// x: [2,1,4096,4096], W1/W2: [1,1,3,3], out: [2,1,1024,1024].
//
// Streaming-stencil design (round 3):
//  - block = 1024 threads = full image width; 4 x-cols per thread (1 float4/row)
//  - pass A: stream 38 x rows; conv1 partial row-sums rotate through registers
//    (x is NEVER staged in LDS -> kills the 16-way bank conflicts of r1/r2);
//    pool1 pairs -> 18 h2 rows written once to LDS (148 KB)
//  - h2 col halo = image edge = literal zero cols in LDS (block spans full W)
//  - ONE barrier; pass B: stream 18 h2 rows from LDS, same rotation,
//    conv2+pool2 -> 8 coalesced output rows
//  - grid = 128 bands x 2 imgs = 256 blocks = 1 per CU, 16 waves/CU

#define HIMG 4096
#define ODIM 1024
#define H2W  2048
#define DOUT 8       // output rows per band
#define SHROWS 18    // 2*DOUT+2 h2 rows in LDS
#define SHSTR 2052   // row stride; SH col = h2 col + 2; cols 1 and 2050 are zero halo

__global__ __launch_bounds__(1024, 4)
void fused_net(const float* __restrict__ x, const float* __restrict__ W1,
               const float* __restrict__ W2, float* __restrict__ out)
{
    __shared__ float h2s[SHROWS][SHSTR];

    const int tid  = threadIdx.x;
    const int lane = tid & 63;
    const int o0   = blockIdx.x * DOUT;
    const int img  = blockIdx.y;
    const long xoff = (long)img * HIMG * HIMG;

    float w1[9], w2[9];
#pragma unroll
    for (int i = 0; i < 9; ++i) { w1[i] = W1[i]; w2[i] = W2[i]; }

    // zero halo cols (h2 col -1 and 2048 = conv2 zero padding at image edges)
    if (tid < SHROWS)                   h2s[tid][1]       = 0.f;
    if (tid >= 64 && tid < 64 + SHROWS) h2s[tid - 64][2050] = 0.f;

    // ---------------- pass A: conv1 + pool1, streaming ----------------
    float accA[4] = {0.f, 0.f, 0.f, 0.f};   // partials for conv row gy-1
    float accB[4] = {0.f, 0.f, 0.f, 0.f};   // partials for conv row gy
    const int xr0 = 4 * o0 - 3;              // first x row of band
    const int x0  = 4 * tid;                 // first x col of this thread

    auto rowA = [&](int t, float (&dd)[4]) {
        const int gy = xr0 + t;
        float4 v = make_float4(0.f, 0.f, 0.f, 0.f);
        float xl = 0.f, xr = 0.f;
        if ((unsigned)gy < (unsigned)HIMG) {          // wave-uniform branch
            const float* xrow = x + xoff + (long)gy * HIMG;
            v  = *(const float4*)(xrow + x0);
            xl = __shfl_up(v.w, 1);
            xr = __shfl_down(v.x, 1);
            if (lane == 0)  xl = (tid > 0)    ? xrow[x0 - 1] : 0.f;
            if (lane == 63) xr = (tid < 1023) ? xrow[x0 + 4] : 0.f;
        }
        const float xv[6] = {xl, v.x, v.y, v.z, v.w, xr};
#pragma unroll
        for (int j = 0; j < 4; ++j) {
            float d = accA[j];                               // completes row gy-1 (tap row 2)
            d = fmaf(w1[6], xv[j], d); d = fmaf(w1[7], xv[j+1], d); d = fmaf(w1[8], xv[j+2], d);
            float a = accB[j];                               // row gy gets tap row 1
            a = fmaf(w1[3], xv[j], a); a = fmaf(w1[4], xv[j+1], a); a = fmaf(w1[5], xv[j+2], a);
            float b = w1[0] * xv[j];                         // row gy+1 gets tap row 0
            b = fmaf(w1[1], xv[j+1], b); b = fmaf(w1[2], xv[j+2], b);
            dd[j] = d; accA[j] = a; accB[j] = b;
        }
    };

    float stash[4], done[4];
    rowA(0, done);          // prime the rotation (completions discarded)
    rowA(1, done);
#pragma unroll 2
    for (int tp = 1; tp < 19; ++tp) {
        rowA(2 * tp,     stash);   // even conv row 2P
        rowA(2 * tp + 1, done);    // odd conv row 2P+1
        const int srow = tp - 1;
        const int Pg = 2 * o0 - 1 + srow;   // global h2 row
        float2 hv;
        hv.x = fmaxf(fmaxf(stash[0], stash[1]), fmaxf(done[0], done[1]));
        hv.y = fmaxf(fmaxf(stash[2], stash[3]), fmaxf(done[2], done[3]));
        if ((unsigned)Pg >= (unsigned)H2W) hv = make_float2(0.f, 0.f);  // conv2 pad rows
        *(float2*)&h2s[srow][2 * tid + 2] = hv;
    }

    __syncthreads();

    // ---------------- pass B: conv2 + pool2, streaming from LDS ----------------
    float dA[2] = {0.f, 0.f}, dB[2] = {0.f, 0.f};
    auto rowB = [&](int R, float (&dd)[2]) {
        const float* rp = &h2s[R][2 * tid + 1];
        const float s1 = rp[0], s2 = rp[1], s3 = rp[2], s4 = rp[3];
        float d0 = dA[0];
        d0 = fmaf(w2[6], s1, d0); d0 = fmaf(w2[7], s2, d0); d0 = fmaf(w2[8], s3, d0);
        float a0 = dB[0];
        a0 = fmaf(w2[3], s1, a0); a0 = fmaf(w2[4], s2, a0); a0 = fmaf(w2[5], s3, a0);
        float b0 = w2[0] * s1; b0 = fmaf(w2[1], s2, b0); b0 = fmaf(w2[2], s3, b0);
        dd[0] = d0; dA[0] = a0; dB[0] = b0;
        float d1 = dA[1];
        d1 = fmaf(w2[6], s2, d1); d1 = fmaf(w2[7], s3, d1); d1 = fmaf(w2[8], s4, d1);
        float a1 = dB[1];
        a1 = fmaf(w2[3], s2, a1); a1 = fmaf(w2[4], s3, a1); a1 = fmaf(w2[5], s4, a1);
        float b1 = w2[0] * s2; b1 = fmaf(w2[1], s3, b1); b1 = fmaf(w2[2], s4, b1);
        dd[1] = d1; dA[1] = a1; dB[1] = b1;
    };

    float dst[2], ddn[2];
    rowB(0, ddn);           // prime
    rowB(1, ddn);
    const long obase = (long)img * ODIM * ODIM;
#pragma unroll
    for (int rp2 = 1; rp2 < 9; ++rp2) {
        rowB(2 * rp2,     dst);
        rowB(2 * rp2 + 1, ddn);
        const float res = fmaxf(fmaxf(dst[0], dst[1]), fmaxf(ddn[0], ddn[1]));
        out[obase + (long)(o0 + rp2 - 1) * ODIM + tid] = res;
    }
}

extern "C" void kernel_launch(void* const* d_in, const int* in_sizes, int n_in,
                              void* d_out, int out_size, void* d_ws, size_t ws_size,
                              hipStream_t stream) {
    const float* x  = (const float*)d_in[0];
    const float* W1 = (const float*)d_in[1];
    const float* W2 = (const float*)d_in[2];
    float* out = (float*)d_out;

    dim3 grid(ODIM / DOUT, 2);   // 128 bands x 2 images = 256 blocks (1 per CU)
    fused_net<<<grid, dim3(1024), 0, stream>>>(x, W1, W2, out);
}